// Round 13
// baseline (100.137 us; speedup 1.0000x reference)
//
#include <hip/hip_runtime.h>
#include <math.h>

#define A_N      5
#define GRID_HW  52
#define NCLS     80
#define CH       85
#define SCORE_T  0.15f
#define IOU_T    0.5f
#define NEGV     (-1e9f)
#define MAXOUT   10

#define WAVES_PB     4                  // waves per decode block
#define BPW          32                 // boxes per wave
#define WAVE_FLOATS  (BPW * CH)         // 2720 floats = 10,880 B per wave
#define WAVE_F4      (WAVE_FLOATS / 4)  // 680 float4 per wave
#define BPB          (WAVES_PB * BPW)   // 128 boxes per block

#define NMS_THREADS  256
#define NCAP         4096               // register fast-path capacity
#define KR           (NCAP / NMS_THREADS)   // 16 register slots per thread

// fast exp: v_exp_f32 (~1e-7 rel err). Argmax uses raw logits (exact); score
// values have 1.54 tolerance; proven across rounds 4-12 (absmax 0).
__device__ __forceinline__ float fexp(float x) { return __expf(x); }

// async global->LDS, 16B/lane. LDS dest = wave-uniform base + lane*16.
__device__ __forceinline__ void gload_lds16(const float* g, float* l) {
    __builtin_amdgcn_global_load_lds(
        (const __attribute__((address_space(1))) unsigned int*)g,
        (__attribute__((address_space(3))) unsigned int*)l, 16, 0, 0);
}

__global__ void init_counters_kernel(int* __restrict__ counters) {
    counters[0] = 0;   // compacted-slot counter
    counters[1] = 0;   // finished-block ticket
}

// ---------------------------------------------------------------------------
// Fused decode + last-block NMS.
// Decode: 4 independent waves/block, each stages its 32-box segment via
// global_load_lds, wave-local vmcnt drain, 2 lanes/box one-pass softmax,
// ballot-compacted output (1 atomic/wave).
// Then: block barrier -> release fence -> done-ticket. The LAST block (clocks
// still hot) runs NMS: registers hold KR boxes+scores/thread; winner coords
// read as uniform pbox[bi] broadcast; no big LDS (decode occupancy intact).
// ---------------------------------------------------------------------------
__global__ __launch_bounds__(256) void fused_kernel(
    const float* __restrict__ preds,
    const float* __restrict__ anchors,
    float4* __restrict__ pbox, float* __restrict__ pscore,
    float* __restrict__ pcls, float* __restrict__ pscratch,
    int* counters, int N, int capacity, float* __restrict__ out)
{
    __shared__ __align__(16) float dlds[WAVES_PB * WAVE_FLOATS];  // 43.5 KB
    __shared__ float psc[4];
    __shared__ int   pix[4];
    __shared__ float orow[MAXOUT * 6];
    __shared__ int   lastFlag;

    int* counter = counters;        // live-slot counter
    int* done    = counters + 1;    // finished-block ticket

    const int tid  = (int)threadIdx.x;
    const int lane = tid & 63;
    const int wid  = tid >> 6;
    const int wt   = blockIdx.x * WAVES_PB + wid;    // wave-tile (32 boxes)

    // ---------------- decode phase ----------------
    if ((long long)wt * BPW < N) {
        const long long total_f4 = ((long long)N * CH) >> 2;
        const long long base_f4  = (long long)wt * WAVE_F4;
        float* lbase = dlds + wid * WAVE_FLOATS;

#pragma unroll
        for (int i = 0; i < 10; ++i) {
            long long idx = base_f4 + i * 64 + lane;
            if (idx < total_f4) gload_lds16(preds + idx * 4, lbase + i * 256);
        }
        if (lane < 40) {
            long long idx = base_f4 + 640 + lane;
            if (idx < total_f4) gload_lds16(preds + idx * 4, lbase + 640 * 4);
        }

        // wave-local drain of async LDS writes (no block barrier needed here)
        asm volatile("s_waitcnt vmcnt(0)" ::: "memory");
        __builtin_amdgcn_sched_barrier(0);

        const int b  = lane >> 1;           // box within wave segment (0..31)
        const int h  = lane & 1;            // half of the 80 classes
        const int gi = wt * BPW + b;
        const float* bp = lbase + b * CH;
        const float* cl = bp + 5 + h * 40;

        float s = 0.0f;
        float m = -INFINITY;
        int   am = h * 40;
#pragma unroll
        for (int j = 0; j < 40; ++j) {
            float x = cl[j];
            s += fexp(x);
            if (x > m) { m = x; am = h * 40 + j; }
        }
        {
            float m2 = __shfl_xor(m, 1);
            float s2 = __shfl_xor(s, 1);
            int   am2 = __shfl_xor(am, 1);
            s += s2;
            if (m2 > m || (m2 == m && am2 < am)) { m = m2; am = am2; }
        }

        float conf  = 1.0f / (1.0f + fexp(-bp[4]));
        float score = conf * fexp(m) / s;

        bool live = (h == 0) && (gi < N) && (score >= SCORE_T);

        unsigned long long mask = __ballot(live);
        if (mask) {
            int nlive  = __popcll(mask);
            int leader = (int)__ffsll((long long)mask) - 1;
            int base_ = 0;
            if (lane == leader) base_ = atomicAdd(counter, nlive);
            base_ = __shfl(base_, leader);
            if (live) {
                int a = gi % A_N;
                int t = gi / A_N;
                int wx = t % GRID_HW;
                int hy = (t / GRID_HW) % GRID_HW;
                const float inv = 1.0f / (float)GRID_HW;
                float cx = (1.0f / (1.0f + fexp(-bp[0])) + (float)wx) * inv;
                float cy = (1.0f / (1.0f + fexp(-bp[1])) + (float)hy) * inv;
                float bw = fexp(bp[2]) * anchors[2 * a]     * inv;
                float bh = fexp(bp[3]) * anchors[2 * a + 1] * inv;

                int pos = base_ + __popcll(mask & ((1ull << lane) - 1));
                if (pos < capacity) {
                    pbox[pos]   = make_float4(cy - 0.5f * bh, cx - 0.5f * bw,
                                              cy + 0.5f * bh, cx + 0.5f * bw);
                    pscore[pos] = score;
                    pcls[pos]   = (float)am;
                }
            }
        }
    }

    // ---------------- last-block handoff ----------------
    __syncthreads();
    if (tid == 0) {
        __threadfence();                       // release: publish pbox/pscore
        int prev = atomicAdd(done, 1);         // device-scope ticket
        lastFlag = (prev == (int)gridDim.x - 1);
    }
    __syncthreads();
    if (!lastFlag) return;
    __threadfence();                           // acquire: see all blocks' data

    // ---------------- NMS phase (one block, clocks hot) ----------------
    int M = atomicAdd(counter, 0);             // atomic read, coherent
    if (M > capacity) M = capacity;

    if (M <= NCAP) {
        // fast path: everything in registers; no SoA LDS at all
        float4 rb[KR];
        float  rs[KR];
#pragma unroll
        for (int k = 0; k < KR; ++k) {
            int j = tid + (k << 8);
            if (j < M) { rb[k] = pbox[j]; rs[k] = pscore[j]; }
            else       { rs[k] = -INFINITY; rb[k] = make_float4(0.f,0.f,0.f,0.f); }
        }

        for (int it = 0; it < MAXOUT; ++it) {
            float bs = -INFINITY; int bi = -1;
#pragma unroll
            for (int k = 0; k < KR; ++k) {          // ascending j => first-max
                if (rs[k] > bs) { bs = rs[k]; bi = tid + (k << 8); }
            }
#pragma unroll
            for (int off = 32; off; off >>= 1) {    // score desc, idx asc
                float os = __shfl_xor(bs, off);
                int   oi = __shfl_xor(bi, off);
                if (os > bs || (os == bs && oi != -1 && (bi == -1 || oi < bi))) {
                    bs = os; bi = oi;
                }
            }
            if (lane == 0) { psc[wid] = bs; pix[wid] = bi; }
            __syncthreads();

            bs = psc[0]; bi = pix[0];
#pragma unroll
            for (int w = 1; w < 4; ++w) {
                float os = psc[w]; int oi = pix[w];
                if (os > bs || (os == bs && oi != -1 && (bi == -1 || oi < bi))) {
                    bs = os; bi = oi;
                }
            }
            bool valid = (bi >= 0) && (bs > NEGV * 0.5f);

            float4 wb = make_float4(0.f, 0.f, 0.f, 0.f);
            if (valid) wb = pbox[bi];               // uniform broadcast load

            if (tid == 0) {
                if (valid) {
                    orow[it*6+0] = wb.x; orow[it*6+1] = wb.y;
                    orow[it*6+2] = wb.z; orow[it*6+3] = wb.w;
                    orow[it*6+4] = bs;   orow[it*6+5] = pcls[bi];
                } else {
                    orow[it*6+0] = 0.f; orow[it*6+1] = 0.f; orow[it*6+2] = 0.f;
                    orow[it*6+3] = 0.f; orow[it*6+4] = 0.f; orow[it*6+5] = 0.f;
                }
            }

            if (valid) {
                float a1 = fmaxf(wb.z - wb.x, 0.f) * fmaxf(wb.w - wb.y, 0.f);
#pragma unroll
                for (int k = 0; k < KR; ++k) {      // pure register math
                    int j = tid + (k << 8);
                    if (j == bi) rs[k] = NEGV;      // reference kills selected
                    float ty = fmaxf(wb.x, rb[k].x);
                    float tx = fmaxf(wb.y, rb[k].y);
                    float by = fminf(wb.z, rb[k].z);
                    float bx = fminf(wb.w, rb[k].w);
                    float inter = fmaxf(by - ty, 0.f) * fmaxf(bx - tx, 0.f);
                    float a2 = fmaxf(rb[k].z - rb[k].x, 0.f)
                             * fmaxf(rb[k].w - rb[k].y, 0.f);
                    float iou = inter / (a1 + a2 - inter + 1e-9f);
                    if (iou > IOU_T) rs[k] = NEGV;
                }
            }
            __syncthreads();   // protect psc/pix for next iteration
        }
    } else {
        // fallback: idempotent via pscratch copy (not hit for this bench; M<=4096 proven)
        for (int j = tid; j < M; j += NMS_THREADS) pscratch[j] = pscore[j];
        __syncthreads();

        for (int it = 0; it < MAXOUT; ++it) {
            float bs = -INFINITY; int bi = -1;
            for (int j = tid; j < M; j += NMS_THREADS) {
                float v = pscratch[j];
                if (v > bs) { bs = v; bi = j; }
            }
#pragma unroll
            for (int off = 32; off; off >>= 1) {
                float os = __shfl_xor(bs, off);
                int   oi = __shfl_xor(bi, off);
                if (os > bs || (os == bs && oi != -1 && (bi == -1 || oi < bi))) {
                    bs = os; bi = oi;
                }
            }
            if (lane == 0) { psc[wid] = bs; pix[wid] = bi; }
            __syncthreads();
            bs = psc[0]; bi = pix[0];
#pragma unroll
            for (int w = 1; w < 4; ++w) {
                float os = psc[w]; int oi = pix[w];
                if (os > bs || (os == bs && oi != -1 && (bi == -1 || oi < bi))) {
                    bs = os; bi = oi;
                }
            }
            bool valid = (bi >= 0) && (bs > NEGV * 0.5f);
            float4 wb = make_float4(0.f, 0.f, 0.f, 0.f);
            if (valid) wb = pbox[bi];
            if (tid == 0) {
                if (valid) {
                    orow[it*6+0] = wb.x; orow[it*6+1] = wb.y;
                    orow[it*6+2] = wb.z; orow[it*6+3] = wb.w;
                    orow[it*6+4] = bs;   orow[it*6+5] = pcls[bi];
                    pscratch[bi] = NEGV;
                } else {
                    orow[it*6+0] = 0.f; orow[it*6+1] = 0.f; orow[it*6+2] = 0.f;
                    orow[it*6+3] = 0.f; orow[it*6+4] = 0.f; orow[it*6+5] = 0.f;
                }
            }
            __syncthreads();
            if (valid) {
                float a1 = fmaxf(wb.z - wb.x, 0.f) * fmaxf(wb.w - wb.y, 0.f);
                for (int j = tid; j < M; j += NMS_THREADS) {
                    float4 bj = pbox[j];
                    float ty = fmaxf(wb.x, bj.x);
                    float tx = fmaxf(wb.y, bj.y);
                    float by = fminf(wb.z, bj.z);
                    float bx = fminf(wb.w, bj.w);
                    float inter = fmaxf(by - ty, 0.f) * fmaxf(bx - tx, 0.f);
                    float a2 = fmaxf(bj.z - bj.x, 0.f) * fmaxf(bj.w - bj.y, 0.f);
                    float iou = inter / (a1 + a2 - inter + 1e-9f);
                    if (iou > IOU_T) pscratch[j] = NEGV;
                }
            }
            __syncthreads();
        }
    }

    __syncthreads();
    if (tid < MAXOUT * 6) out[tid] = orow[tid];   // single coalesced write
}

extern "C" void kernel_launch(void* const* d_in, const int* in_sizes, int n_in,
                              void* d_out, int out_size, void* d_ws, size_t ws_size,
                              hipStream_t stream) {
    (void)n_in; (void)out_size;
    const float* preds   = (const float*)d_in[0];
    const float* anchors = (const float*)d_in[1];
    float* out = (float*)d_out;

    int N = in_sizes[0] / CH;   // 216,320 boxes

    // Workspace: [0,64) counters; pbox float4[cap]; pscore, pcls, pscratch.
    char* ws = (char*)d_ws;
    int* counters = (int*)ws;
    size_t avail = (ws_size > 64) ? (ws_size - 64) : 0;
    long long cap = (long long)(avail / (sizeof(float4) + 3 * sizeof(float)));
    if (cap > N) cap = N;
    if (cap < 0) cap = 0;
    int capacity = (int)cap;

    float4* pbox    = (float4*)(ws + 64);
    float* pscore   = (float*)(pbox + capacity);
    float* pcls     = pscore + capacity;
    float* pscratch = pcls + capacity;

    init_counters_kernel<<<1, 1, 0, stream>>>(counters);

    int nBlocks = (N + BPB - 1) / BPB;   // 1690
    fused_kernel<<<nBlocks, 256, 0, stream>>>(
        preds, anchors, pbox, pscore, pcls, pscratch,
        counters, N, capacity, out);
}

// Round 14
// 63.058 us; speedup vs baseline: 1.5880x; 1.5880x over previous
//
#include <hip/hip_runtime.h>
#include <math.h>

#define A_N      5
#define GRID_HW  52
#define NCLS     80
#define CH       85
#define SCORE_T  0.15f
#define IOU_T    0.5f
#define NEGV     (-1e9f)
#define MAXOUT   10

#define WAVES_PB     4                  // waves per decode block
#define BPW          32                 // boxes per wave
#define WAVE_FLOATS  (BPW * CH)         // 2720 floats = 10,880 B per wave
#define WAVE_FULL    10                 // 10 x 64 lanes x 16 B = 640 float4
#define WAVE_TAIL    40                 // +40 float4 = 680 = 2720 floats

#define NMS_THREADS  512                // 8 waves
#define NWAVES       (NMS_THREADS / 64)
#define NCAP         4096               // register fast-path capacity
#define KR           (NCAP / NMS_THREADS)   // 8 register slots per thread

// fast exp: v_exp_f32 (~1e-7 rel err). Argmax uses raw logits (exact); score
// values have 1.54 tolerance; proven across rounds 4-13 (absmax 0).
__device__ __forceinline__ float fexp(float x) { return __expf(x); }

// async global->LDS, 16B/lane. LDS dest = wave-uniform base + lane*16.
__device__ __forceinline__ void gload_lds16(const float* g, float* l) {
    __builtin_amdgcn_global_load_lds(
        (const __attribute__((address_space(1))) unsigned int*)g,
        (__attribute__((address_space(3))) unsigned int*)l, 16, 0, 0);
}

__global__ void init_counter_kernel(int* __restrict__ counter) {
    *counter = 0;
}

// ---------------------------------------------------------------------------
// Decode (unchanged, ~17 us): 4 independent waves/block, each stages its own
// 32-box segment via global_load_lds, wave-local vmcnt drain, 2 lanes/box
// one-pass softmax, ballot-compacted output (1 atomic/wave).
// ---------------------------------------------------------------------------
__global__ __launch_bounds__(256) void decode_kernel(
    const float* __restrict__ preds,
    const float* __restrict__ anchors,
    float4* __restrict__ pbox, float* __restrict__ pscore,
    float* __restrict__ pcls,
    int* __restrict__ counter, int N, int capacity)
{
    __shared__ __align__(16) float lds[WAVES_PB * WAVE_FLOATS];

    const int lane = (int)threadIdx.x & 63;
    const int wid  = (int)threadIdx.x >> 6;
    const int wt   = blockIdx.x * WAVES_PB + wid;   // wave-tile (32 boxes)
    if (wt * BPW >= N) return;                      // whole-wave guard

    const float* gbase = preds + (size_t)wt * WAVE_FLOATS;
    float* lbase = lds + wid * WAVE_FLOATS;

#pragma unroll
    for (int i = 0; i < WAVE_FULL; ++i)
        gload_lds16(gbase + (size_t)(i * 64 + lane) * 4, lbase + i * 256);
    if (lane < WAVE_TAIL)
        gload_lds16(gbase + (size_t)(WAVE_FULL * 64 + lane) * 4,
                    lbase + WAVE_FULL * 256);

    asm volatile("s_waitcnt vmcnt(0)" ::: "memory");
    __builtin_amdgcn_sched_barrier(0);

    const int b  = lane >> 1;            // box within wave segment (0..31)
    const int h  = lane & 1;             // half of the 80 classes
    const int gi = wt * BPW + b;
    const float* bp = lbase + b * CH;
    const float* cl = bp + 5 + h * 40;

    float s = 0.0f;
    float m = -INFINITY;
    int   am = h * 40;
#pragma unroll
    for (int j = 0; j < 40; ++j) {
        float x = cl[j];
        s += fexp(x);
        if (x > m) { m = x; am = h * 40 + j; }
    }
    {
        float m2 = __shfl_xor(m, 1);
        float s2 = __shfl_xor(s, 1);
        int   am2 = __shfl_xor(am, 1);
        s += s2;
        if (m2 > m || (m2 == m && am2 < am)) { m = m2; am = am2; }
    }

    float conf  = 1.0f / (1.0f + fexp(-bp[4]));
    float score = conf * fexp(m) / s;

    bool live = (h == 0) && (gi < N) && (score >= SCORE_T);

    unsigned long long mask = __ballot(live);
    if (mask) {
        int nlive  = __popcll(mask);
        int leader = (int)__ffsll((long long)mask) - 1;
        int base_ = 0;
        if (lane == leader) base_ = atomicAdd(counter, nlive);
        base_ = __shfl(base_, leader);
        if (live) {
            int a = gi % A_N;
            int t = gi / A_N;
            int wx = t % GRID_HW;
            int hy = (t / GRID_HW) % GRID_HW;
            const float inv = 1.0f / (float)GRID_HW;
            float cx = (1.0f / (1.0f + fexp(-bp[0])) + (float)wx) * inv;
            float cy = (1.0f / (1.0f + fexp(-bp[1])) + (float)hy) * inv;
            float bw = fexp(bp[2]) * anchors[2 * a]     * inv;
            float bh = fexp(bp[3]) * anchors[2 * a + 1] * inv;

            int pos = base_ + __popcll(mask & ((1ull << lane) - 1));
            if (pos < capacity) {
                pbox[pos]   = make_float4(cy - 0.5f * bh, cx - 0.5f * bw,
                                          cy + 0.5f * bh, cx + 0.5f * bw);
                pscore[pos] = score;
                pcls[pos]   = (float)am;
            }
        }
    }
}

// ---------------------------------------------------------------------------
// NMS: one block, 512 threads (8 waves). Fast path (M <= 4096): KR=8
// boxes+scores per thread in REGISTERS (~70 VGPR total incl. temps — fits
// without spill; launch_bounds(512,1) removes any occupancy pressure on the
// allocator). Round 13's spill (VGPR=76 < needed, WRITE_SIZE 245KB of
// scratch) was the 30-us cost; KR=16 -> 8 eliminates it.
// Per iter: 8 reg compares -> 6-step wave butterfly -> 8 partials -> 16
// broadcast LDS reads -> uniform winner load -> register IoU suppression.
// ---------------------------------------------------------------------------
__global__ __launch_bounds__(NMS_THREADS, 1) void nms_kernel(
    const float4* __restrict__ pbox, float* __restrict__ pscore,
    const float* __restrict__ pcls, const int* __restrict__ counter,
    int capacity, float* __restrict__ pscratch, float* __restrict__ out)
{
    __shared__ float psc[NWAVES];
    __shared__ int   pix[NWAVES];
    __shared__ float orow[MAXOUT * 6];

    int M = *counter;
    if (M > capacity) M = capacity;
    const int tid  = (int)threadIdx.x;
    const int lane = tid & 63;
    const int wid  = tid >> 6;

    if (M <= NCAP) {
        // -------- fast path: everything in registers --------
        float4 rb[KR];
        float  rs[KR];
#pragma unroll
        for (int k = 0; k < KR; ++k) {
            int j = tid + (k << 9);                 // k * 512
            if (j < M) { rb[k] = pbox[j]; rs[k] = pscore[j]; }
            else       { rs[k] = -INFINITY; rb[k] = make_float4(0.f,0.f,0.f,0.f); }
        }

        for (int it = 0; it < MAXOUT; ++it) {
            float bs = -INFINITY; int bi = -1;
#pragma unroll
            for (int k = 0; k < KR; ++k) {          // ascending j => first-max
                if (rs[k] > bs) { bs = rs[k]; bi = tid + (k << 9); }
            }
#pragma unroll
            for (int off = 32; off; off >>= 1) {    // score desc, idx asc
                float os = __shfl_xor(bs, off);
                int   oi = __shfl_xor(bi, off);
                if (os > bs || (os == bs && oi != -1 && (bi == -1 || oi < bi))) {
                    bs = os; bi = oi;
                }
            }
            if (lane == 0) { psc[wid] = bs; pix[wid] = bi; }
            __syncthreads();

            bs = psc[0]; bi = pix[0];
#pragma unroll
            for (int w = 1; w < NWAVES; ++w) {
                float os = psc[w]; int oi = pix[w];
                if (os > bs || (os == bs && oi != -1 && (bi == -1 || oi < bi))) {
                    bs = os; bi = oi;
                }
            }
            bool valid = (bi >= 0) && (bs > NEGV * 0.5f);

            float4 wb = make_float4(0.f, 0.f, 0.f, 0.f);
            if (valid) wb = pbox[bi];               // uniform broadcast, L2-hot

            if (tid == 0) {
                if (valid) {
                    orow[it*6+0] = wb.x; orow[it*6+1] = wb.y;
                    orow[it*6+2] = wb.z; orow[it*6+3] = wb.w;
                    orow[it*6+4] = bs;   orow[it*6+5] = pcls[bi];
                } else {
                    orow[it*6+0] = 0.f; orow[it*6+1] = 0.f; orow[it*6+2] = 0.f;
                    orow[it*6+3] = 0.f; orow[it*6+4] = 0.f; orow[it*6+5] = 0.f;
                }
            }

            if (valid) {
                float a1 = fmaxf(wb.z - wb.x, 0.f) * fmaxf(wb.w - wb.y, 0.f);
#pragma unroll
                for (int k = 0; k < KR; ++k) {      // pure register math
                    int j = tid + (k << 9);
                    if (j == bi) rs[k] = NEGV;      // reference kills selected
                    float ty = fmaxf(wb.x, rb[k].x);
                    float tx = fmaxf(wb.y, rb[k].y);
                    float by = fminf(wb.z, rb[k].z);
                    float bx = fminf(wb.w, rb[k].w);
                    float inter = fmaxf(by - ty, 0.f) * fmaxf(bx - tx, 0.f);
                    float a2 = fmaxf(rb[k].z - rb[k].x, 0.f)
                             * fmaxf(rb[k].w - rb[k].y, 0.f);
                    float iou = inter / (a1 + a2 - inter + 1e-9f);
                    if (iou > IOU_T) rs[k] = NEGV;
                }
            }
            __syncthreads();   // protect psc/pix for next iteration
        }
    } else {
        // -------- fallback: idempotent via pscratch (not hit: M ~1500) -----
        for (int j = tid; j < M; j += NMS_THREADS) pscratch[j] = pscore[j];
        __syncthreads();

        for (int it = 0; it < MAXOUT; ++it) {
            float bs = -INFINITY; int bi = -1;
            for (int j = tid; j < M; j += NMS_THREADS) {
                float v = pscratch[j];
                if (v > bs) { bs = v; bi = j; }
            }
#pragma unroll
            for (int off = 32; off; off >>= 1) {
                float os = __shfl_xor(bs, off);
                int   oi = __shfl_xor(bi, off);
                if (os > bs || (os == bs && oi != -1 && (bi == -1 || oi < bi))) {
                    bs = os; bi = oi;
                }
            }
            if (lane == 0) { psc[wid] = bs; pix[wid] = bi; }
            __syncthreads();
            bs = psc[0]; bi = pix[0];
#pragma unroll
            for (int w = 1; w < NWAVES; ++w) {
                float os = psc[w]; int oi = pix[w];
                if (os > bs || (os == bs && oi != -1 && (bi == -1 || oi < bi))) {
                    bs = os; bi = oi;
                }
            }
            bool valid = (bi >= 0) && (bs > NEGV * 0.5f);
            float4 wb = make_float4(0.f, 0.f, 0.f, 0.f);
            if (valid) wb = pbox[bi];
            if (tid == 0) {
                if (valid) {
                    orow[it*6+0] = wb.x; orow[it*6+1] = wb.y;
                    orow[it*6+2] = wb.z; orow[it*6+3] = wb.w;
                    orow[it*6+4] = bs;   orow[it*6+5] = pcls[bi];
                    pscratch[bi] = NEGV;
                } else {
                    orow[it*6+0] = 0.f; orow[it*6+1] = 0.f; orow[it*6+2] = 0.f;
                    orow[it*6+3] = 0.f; orow[it*6+4] = 0.f; orow[it*6+5] = 0.f;
                }
            }
            __syncthreads();
            if (valid) {
                float a1 = fmaxf(wb.z - wb.x, 0.f) * fmaxf(wb.w - wb.y, 0.f);
                for (int j = tid; j < M; j += NMS_THREADS) {
                    float4 bj = pbox[j];
                    float ty = fmaxf(wb.x, bj.x);
                    float tx = fmaxf(wb.y, bj.y);
                    float by = fminf(wb.z, bj.z);
                    float bx = fminf(wb.w, bj.w);
                    float inter = fmaxf(by - ty, 0.f) * fmaxf(bx - tx, 0.f);
                    float a2 = fmaxf(bj.z - bj.x, 0.f) * fmaxf(bj.w - bj.y, 0.f);
                    float iou = inter / (a1 + a2 - inter + 1e-9f);
                    if (iou > IOU_T) pscratch[j] = NEGV;
                }
            }
            __syncthreads();
        }
    }

    __syncthreads();
    if (tid < MAXOUT * 6) out[tid] = orow[tid];   // single coalesced write
}

extern "C" void kernel_launch(void* const* d_in, const int* in_sizes, int n_in,
                              void* d_out, int out_size, void* d_ws, size_t ws_size,
                              hipStream_t stream) {
    (void)n_in; (void)out_size;
    const float* preds   = (const float*)d_in[0];
    const float* anchors = (const float*)d_in[1];
    float* out = (float*)d_out;

    int N = in_sizes[0] / CH;   // 216,320 boxes

    // Workspace: [0,64) counter; pbox float4[cap]; pscore, pcls, pscratch.
    char* ws = (char*)d_ws;
    int* counter = (int*)ws;
    size_t avail = (ws_size > 64) ? (ws_size - 64) : 0;
    long long cap = (long long)(avail / (sizeof(float4) + 3 * sizeof(float)));
    if (cap > N) cap = N;
    if (cap < 0) cap = 0;
    int capacity = (int)cap;

    float4* pbox    = (float4*)(ws + 64);
    float* pscore   = (float*)(pbox + capacity);
    float* pcls     = pscore + capacity;
    float* pscratch = pcls + capacity;

    init_counter_kernel<<<1, 1, 0, stream>>>(counter);

    int nBlocks = (N + WAVES_PB * BPW - 1) / (WAVES_PB * BPW);   // 1690
    decode_kernel<<<nBlocks, 256, 0, stream>>>(
        preds, anchors, pbox, pscore, pcls, counter, N, capacity);
    nms_kernel<<<1, NMS_THREADS, 0, stream>>>(
        pbox, pscore, pcls, counter, capacity, pscratch, out);
}